// Round 1
// baseline (2999.698 us; speedup 1.0000x reference)
//
#include <hip/hip_runtime.h>
#include <hip/hip_bf16.h>

#define NN 100000
#define EE 1600000
#define FIN 1433
#define DD 64

// ---------------- CSR build ----------------

__global__ void hist_kernel(const int* __restrict__ dst, int* __restrict__ deg, int e) {
    int i = blockIdx.x * 256 + threadIdx.x;
    if (i < e) atomicAdd(&deg[dst[i]], 1);
}

__global__ void scan1_kernel(const int* __restrict__ deg, int* __restrict__ out,
                             int* __restrict__ bsums, int n) {
    int i = blockIdx.x * 1024 + threadIdx.x;
    int lane = threadIdx.x & 63, w = threadIdx.x >> 6;
    int val = (i < n) ? deg[i] : 0;
    for (int off = 1; off < 64; off <<= 1) {
        int t = __shfl_up(val, off);
        if (lane >= off) val += t;
    }
    __shared__ int wsum[16];
    if (lane == 63) wsum[w] = val;
    __syncthreads();
    if (threadIdx.x < 16) {
        int s = wsum[threadIdx.x];
        for (int off = 1; off < 16; off <<= 1) {
            int t = __shfl_up(s, off);
            if (threadIdx.x >= off) s += t;
        }
        wsum[threadIdx.x] = s;
    }
    __syncthreads();
    if (w > 0) val += wsum[w - 1];
    if (i < n) out[i] = val;
    if (threadIdx.x == 1023) bsums[blockIdx.x] = val;
}

__global__ void scan2_kernel(int* __restrict__ bsums, int nb) {
    int i = threadIdx.x;               // 128 threads, 2 waves
    int lane = threadIdx.x & 63, w = threadIdx.x >> 6;
    int val = (i < nb) ? bsums[i] : 0;
    for (int off = 1; off < 64; off <<= 1) {
        int t = __shfl_up(val, off);
        if (lane >= off) val += t;
    }
    __shared__ int wsum[2];
    if (lane == 63) wsum[w] = val;
    __syncthreads();
    if (w > 0) val += wsum[0];
    if (i < nb) bsums[i] = val;
}

__global__ void scan3_kernel(const int* __restrict__ scanb, const int* __restrict__ deg,
                             const int* __restrict__ bsums, int* __restrict__ indptr,
                             int* __restrict__ cursor, int n) {
    int i = blockIdx.x * 1024 + threadIdx.x;
    if (i < n) {
        int off = (blockIdx.x > 0) ? bsums[blockIdx.x - 1] : 0;
        int incl = scanb[i] + off;
        indptr[i + 1] = incl;
        cursor[i] = incl - deg[i];
        if (i == 0) indptr[0] = 0;
    }
}

__global__ void scatter_kernel(const int* __restrict__ src, const int* __restrict__ dst,
                               int* __restrict__ cursor, int* __restrict__ csr_src, int e) {
    int i = blockIdx.x * 256 + threadIdx.x;
    if (i < e) {
        int pos = atomicAdd(&cursor[dst[i]], 1);
        csr_src[pos] = src[i];
    }
}

// ---------------- f32 tiled GEMM: C[M,64] = A[M,K] @ B[K,64] (+bias) ----------------
// tile 128 rows x 64 cols, K-chunk 32, 256 threads, 8x4 per thread.
// grid.y selects among up to 3 (B, C) pairs (fused QKV); bias/C2 optional.

__global__ __launch_bounds__(256) void gemm_kernel(
    const float* __restrict__ A,
    const float* __restrict__ B0, const float* __restrict__ B1, const float* __restrict__ B2,
    const float* __restrict__ bias,
    float* __restrict__ C0, float* __restrict__ C1, float* __restrict__ C2sel,
    float* __restrict__ Cdup,
    int M, int K, int lda)
{
    __shared__ float As[128][33];
    __shared__ float Bs[32][64];
    const float* B = (blockIdx.y == 0) ? B0 : (blockIdx.y == 1) ? B1 : B2;
    float* C = (blockIdx.y == 0) ? C0 : (blockIdx.y == 1) ? C1 : C2sel;

    int t = threadIdx.x;
    int bm = blockIdx.x * 128;
    int tn = t & 15;       // col group: cols 4*tn
    int tm = t >> 4;       // row group: rows 8*tm..8*tm+7
    float acc[8][4] = {};

    for (int k0 = 0; k0 < K; k0 += 32) {
        for (int idx = t; idx < 128 * 32; idx += 256) {
            int r = idx >> 5, kk = idx & 31;
            int gr = bm + r, gk = k0 + kk;
            As[r][kk] = (gr < M && gk < K) ? A[(size_t)gr * lda + gk] : 0.f;
        }
        for (int idx = t; idx < 32 * 64; idx += 256) {
            int kk = idx >> 6, c = idx & 63;
            int gk = k0 + kk;
            Bs[kk][c] = (gk < K) ? B[(size_t)gk * 64 + c] : 0.f;
        }
        __syncthreads();
#pragma unroll
        for (int kk = 0; kk < 32; ++kk) {
            float4 bv = *(const float4*)&Bs[kk][tn * 4];
#pragma unroll
            for (int j = 0; j < 8; ++j) {
                float a = As[tm * 8 + j][kk];
                acc[j][0] += a * bv.x;
                acc[j][1] += a * bv.y;
                acc[j][2] += a * bv.z;
                acc[j][3] += a * bv.w;
            }
        }
        __syncthreads();
    }
#pragma unroll
    for (int j = 0; j < 8; ++j) {
        int row = bm + tm * 8 + j;
        if (row < M) {
#pragma unroll
            for (int c = 0; c < 4; ++c) {
                float val = acc[j][c] + (bias ? bias[tn * 4 + c] : 0.f);
                C[(size_t)row * 64 + tn * 4 + c] = val;
                if (Cdup) Cdup[(size_t)row * 64 + tn * 4 + c] = val;
            }
        }
    }
}

// ---------------- LayerNorm: one wave per node ----------------

__global__ __launch_bounds__(256) void ln_kernel(const float* __restrict__ x,
                                                 float* __restrict__ h,
                                                 const float* __restrict__ scale,
                                                 const float* __restrict__ bias, int n) {
    int wave = threadIdx.x >> 6, lane = threadIdx.x & 63;
    int i = blockIdx.x * 4 + wave;
    if (i >= n) return;
    float v = x[(size_t)i * 64 + lane];
    float s = v, sq = v * v;
#pragma unroll
    for (int off = 1; off < 64; off <<= 1) {
        s += __shfl_xor(s, off);
        sq += __shfl_xor(sq, off);
    }
    float mu = s * (1.f / 64.f);
    float var = sq * (1.f / 64.f) - mu * mu;
    float r = 1.f / sqrtf(var + 1e-5f);
    h[(size_t)i * 64 + lane] = (v - mu) * r * scale[lane] + bias[lane];
}

// ---------------- fused attention + Wo + gate + residual: one wave per dst node ----------------
// lane = h*16 + d (H=4, DH=16). Linear online softmax (no max subtraction; logits are O(0.2)).

__global__ __launch_bounds__(256) void attn_kernel(
    const float* __restrict__ q, const float* __restrict__ k, const float* __restrict__ v,
    const int* __restrict__ indptr, const int* __restrict__ csr_src,
    const float* __restrict__ Wo, const float* __restrict__ gateW,
    const float* __restrict__ gateB,
    const float* __restrict__ xres, const float* __restrict__ x0,
    float* __restrict__ xout, int n)
{
    int wave = threadIdx.x >> 6, lane = threadIdx.x & 63;
    int i = blockIdx.x * 4 + wave;
    if (i >= n) return;

    float ql = q[(size_t)i * 64 + lane];
    int e0 = indptr[i], e1 = indptr[i + 1];

    float acc = 0.f, denom = 0.f;
    // software pipeline depth 1
    int s_cur = (e0 < e1) ? csr_src[e0] : 0;
    float kl = (e0 < e1) ? k[(size_t)s_cur * 64 + lane] : 0.f;
    float vl = (e0 < e1) ? v[(size_t)s_cur * 64 + lane] : 0.f;

    for (int e = e0; e < e1; ++e) {
        int s_nxt = (e + 1 < e1) ? csr_src[e + 1] : 0;
        float kn = (e + 1 < e1) ? k[(size_t)s_nxt * 64 + lane] : 0.f;
        float vn = (e + 1 < e1) ? v[(size_t)s_nxt * 64 + lane] : 0.f;

        float p = ql * kl;
        p += __shfl_xor(p, 1);
        p += __shfl_xor(p, 2);
        p += __shfl_xor(p, 4);
        p += __shfl_xor(p, 8);          // per-head dot, broadcast to 16 lanes
        float ex = expf(p * 0.25f);     // scale = DH^-0.5 = 0.25
        denom += ex;
        acc += ex * vl;

        kl = kn; vl = vn;
    }
    float agg = acc / (denom + 1e-9f);

    // out = agg_flat @ Wo  (lane j holds out_j)
    float out = 0.f;
#pragma unroll
    for (int kk = 0; kk < 64; ++kk) {
        float a = __shfl(agg, kk);
        out += a * Wo[kk * 64 + lane];
    }

    float res = xres[(size_t)i * 64 + lane];
    float gin = out * gateW[lane] + res * gateW[64 + lane] + (out - res) * gateW[128 + lane];
#pragma unroll
    for (int off = 1; off < 64; off <<= 1) gin += __shfl_xor(gin, off);
    float z = gin + gateB[0];
    float g = 1.f / (1.f + expf(-z));
    float mixed = g * out + (1.f - g) * res;
    float xn = 0.9f * mixed + 0.1f * x0[(size_t)i * 64 + lane];
    xout[(size_t)i * 64 + lane] = xn;
}

// ---------------- launch ----------------

extern "C" void kernel_launch(void* const* d_in, const int* in_sizes, int n_in,
                              void* d_out, int out_size, void* d_ws, size_t ws_size,
                              hipStream_t stream) {
    const float* nodes    = (const float*)d_in[0];
    const int*   edge_idx = (const int*)d_in[1];
    const float* emb_W    = (const float*)d_in[2];
    const float* emb_b    = (const float*)d_in[3];
    const float* ln_scale = (const float*)d_in[4];
    const float* ln_bias  = (const float*)d_in[5];
    const float* Wq       = (const float*)d_in[6];
    const float* Wk       = (const float*)d_in[7];
    const float* Wv       = (const float*)d_in[8];
    const float* Wo       = (const float*)d_in[9];
    const float* gate_W   = (const float*)d_in[10];
    const float* gate_b   = (const float*)d_in[11];
    float* out = (float*)d_out;

    float* x0 = (float*)d_ws;
    float* x  = x0 + (size_t)NN * 64;
    float* h  = x  + (size_t)NN * 64;
    float* q  = h  + (size_t)NN * 64;
    float* kb = q  + (size_t)NN * 64;
    float* vb = kb + (size_t)NN * 64;
    int* deg    = (int*)(vb + (size_t)NN * 64);
    int* scanb  = deg + NN;
    int* bsums  = scanb + NN;
    int* indptr = bsums + 256;
    int* cursor = indptr + NN + 1;
    int* csr    = cursor + NN;

    const int* src = edge_idx;
    const int* dst = edge_idx + EE;

    hipMemsetAsync(deg, 0, NN * sizeof(int), stream);
    hist_kernel<<<EE / 256, 256, 0, stream>>>(dst, deg, EE);
    int nsb = (NN + 1023) / 1024;   // 98
    scan1_kernel<<<nsb, 1024, 0, stream>>>(deg, scanb, bsums, NN);
    scan2_kernel<<<1, 128, 0, stream>>>(bsums, nsb);
    scan3_kernel<<<nsb, 1024, 0, stream>>>(scanb, deg, bsums, indptr, cursor, NN);
    scatter_kernel<<<EE / 256, 256, 0, stream>>>(src, dst, cursor, csr, EE);

    // embedding: x0 = nodes @ emb_W + emb_b ; x = x0
    {
        dim3 grid((NN + 127) / 128, 1);
        gemm_kernel<<<grid, 256, 0, stream>>>(nodes, emb_W, emb_W, emb_W, emb_b,
                                              x0, x0, x0, x, NN, FIN, FIN);
    }

    for (int l = 0; l < 3; ++l) {
        ln_kernel<<<NN / 4, 256, 0, stream>>>(x, h, ln_scale + l * 64, ln_bias + l * 64, NN);
        dim3 grid((NN + 127) / 128, 3);
        gemm_kernel<<<grid, 256, 0, stream>>>(h, Wq + l * 4096, Wk + l * 4096, Wv + l * 4096,
                                              nullptr, q, kb, vb, nullptr, NN, DD, DD);
        attn_kernel<<<NN / 4, 256, 0, stream>>>(q, kb, vb, indptr, csr,
                                                Wo + l * 4096, gate_W + l * 192, gate_b + l,
                                                x, x0, (l == 2) ? out : x, NN);
    }
}